// Round 12
// baseline (257.928 us; speedup 1.0000x reference)
//
#include <hip/hip_runtime.h>
#include <hip/hip_bf16.h>
#include <math.h>

#define TPB 256

typedef unsigned short u16;
typedef __attribute__((ext_vector_type(8))) short bf16x8;
typedef __attribute__((ext_vector_type(4))) float f32x4;

constexpr int cB    = 4;
constexpr int cNQ   = 4096;
constexpr int cKV   = 64;
constexpr int cNK   = 28736;
constexpr int cNKR  = 28672;
constexpr int cNLM  = 7232;   // 7*1024 + 64
constexpr int cNPOOL= 7168;
constexpr int cKT   = 32;
constexpr int cKSPLIT = 4;
constexpr int cQT   = 128;
constexpr float cSCALE  = 0.0625f;                 // 1/sqrt(256)
constexpr float cLOGTH  = 0.14391156831212787f;    // ln(10000)/64
constexpr float cKOFF   = 1.3862943611198906f;     // 2*ln(2)
constexpr float cTHR    = 8.0f;                    // defer-max threshold

// ---------------- helpers ----------------
__device__ __forceinline__ u16 f2bf(float x) {
  __hip_bfloat16 h = __float2bfloat16(x);
  return __builtin_bit_cast(u16, h);
}
__device__ __forceinline__ float bf2f(u16 u) {
  return __builtin_bit_cast(float, ((unsigned)u) << 16);
}

template<int CTRL>
__device__ __forceinline__ float dpp_mov(float v) {
  return __builtin_bit_cast(float,
      __builtin_amdgcn_update_dpp(0, __builtin_bit_cast(int, v), CTRL, 0xf, 0xf, true));
}
__device__ __forceinline__ float redmax16(float v) {
  v = fmaxf(v, dpp_mov<0x128>(v));
  v = fmaxf(v, dpp_mov<0x124>(v));
  v = fmaxf(v, dpp_mov<0x122>(v));
  v = fmaxf(v, dpp_mov<0x121>(v));
  return v;
}

__device__ __forceinline__ void gl_lds16(const u16* g, u16* l) {
  __builtin_amdgcn_global_load_lds(
      (const __attribute__((address_space(1))) unsigned int*)g,
      (__attribute__((address_space(3))) unsigned int*)l, 16, 0, 0);
}

__device__ __forceinline__ void mac4(float4& a, const float4 x,
    const float4 w0, const float4 w1, const float4 w2, const float4 w3) {
  a.x = fmaf(x.x,w0.x, fmaf(x.y,w1.x, fmaf(x.z,w2.x, fmaf(x.w,w3.x, a.x))));
  a.y = fmaf(x.x,w0.y, fmaf(x.y,w1.y, fmaf(x.z,w2.y, fmaf(x.w,w3.y, a.y))));
  a.z = fmaf(x.x,w0.z, fmaf(x.y,w1.z, fmaf(x.z,w2.z, fmaf(x.w,w3.z, a.z))));
  a.w = fmaf(x.x,w0.w, fmaf(x.y,w1.w, fmaf(x.z,w2.w, fmaf(x.w,w3.w, a.w))));
}

// stage one 256n x 64k bf16 B-tile (pre-swizzled global) into LDS via global_load_lds
__device__ __forceinline__ void stageB(const u16* __restrict__ WT, int st, u16* sB, int tid) {
  #pragma unroll
  for (int r = 0; r < 16; ++r) {
    int cu = r*128 + (tid & ~63);
    int c  = r*128 + tid;
    gl_lds16(WT + (size_t)(c >> 3)*256 + (size_t)(st*8 + (c & 7))*8,
             sB + (size_t)cu*8);
  }
}

// stage a full 256n x 64k bf16 weight (pre-swizzled [n][64] global) into LDS
__device__ __forceinline__ void stageW64(const u16* __restrict__ WT, u16* sB, int tid) {
  #pragma unroll
  for (int r = 0; r < 8; ++r) {
    int idx = r*256 + tid;
    gl_lds16(WT + (size_t)idx*8, sB + (size_t)(r*256 + (tid & ~63))*8);
  }
}

// ---------------------------------------------------------------------------
// wprep: transpose+bf16-convert+pre-swizzle weights.
// ---------------------------------------------------------------------------
__global__ __launch_bounds__(TPB) void wprep_kernel(
    const float* __restrict__ Wq, const float* __restrict__ Wo,
    const float* __restrict__ Wk, const float* __restrict__ Wv,
    u16* __restrict__ WqT, u16* __restrict__ WoThi, u16* __restrict__ WoTlo,
    u16* __restrict__ WkT, u16* __restrict__ WvT)
{
  __shared__ float sT[32][36];
  const int tid = threadIdx.x;
  const int bidx = blockIdx.x;

  const float* W; int t_idx; bool small; bool isWo = false;
  u16 *out0 = nullptr, *out1 = nullptr;
  if (bidx < 64)       { W = Wq; t_idx = bidx;      small = false; out0 = WqT; }
  else if (bidx < 128) { W = Wo; t_idx = bidx-64;   small = false; isWo = true; out0 = WoThi; out1 = WoTlo; }
  else if (bidx < 144) { W = Wk; t_idx = bidx-128;  small = true;  out0 = WkT; }
  else                 { W = Wv; t_idx = bidx-144;  small = true;  out0 = WvT; }

  const int k0 = (t_idx >> 3) * 32;
  const int n0 = (t_idx & 7) * 32;

  {
    int r = tid >> 3, c4 = (tid & 7) * 4;
    *(float4*)&sT[r][c4] = *(const float4*)(W + (size_t)(k0 + r)*256 + n0 + c4);
  }
  __syncthreads();

  const int n  = n0 + (tid >> 3);
  const int kq = (tid & 7) * 4;
  float v[4];
  #pragma unroll
  for (int j = 0; j < 4; ++j) v[j] = sT[kq + j][tid >> 3];

  const int s = (k0 + kq) >> 3;
  const int p = small ? (s ^ (n & 7)) : ((s & ~7) | ((s & 7) ^ (n & 7)));
  const int rowlen = small ? 64 : 256;
  const size_t off = (size_t)n*rowlen + p*8 + (kq & 4);

  if (!isWo) {
    ushort4 h; h.x = f2bf(v[0]); h.y = f2bf(v[1]); h.z = f2bf(v[2]); h.w = f2bf(v[3]);
    *(ushort4*)(out0 + off) = h;
  } else {
    ushort4 h, l;
    #pragma unroll
    for (int j = 0; j < 4; ++j) {
      u16 hb = f2bf(v[j]);
      u16 lb = f2bf(v[j] - bf2f(hb));
      ((u16*)&h)[j] = hb; ((u16*)&l)[j] = lb;
    }
    *(ushort4*)(out0 + off) = h;
    *(ushort4*)(out1 + off) = l;
  }
}

// ---------------------------------------------------------------------------
// projq_mfma: qr = rope(q @ Wq + bq) * scale, bf16 out.
// ---------------------------------------------------------------------------
__global__ __launch_bounds__(128) void projq_mfma(
    const float* __restrict__ X, const u16* __restrict__ WT,
    const float* __restrict__ bias, u16* __restrict__ Y)
{
  __shared__ u16 lds[32768];        // 64KB: sA 32K | sB 32K ; C overlays both
  u16* sA = lds;
  u16* sB = lds + 16384;
  float* sC = (float*)lds;          // [64][256] f32
  __shared__ float sfreq[64];
  __shared__ float sbias[256];

  const int tid  = threadIdx.x;
  const int lane = tid & 63;
  const int w    = tid >> 6;
  const int lh   = lane & 15;
  const int lq   = lane >> 4;
  const int n0   = blockIdx.x * 16;

  if (tid < 64) sfreq[tid] = __expf(-(float)tid * cLOGTH);
  if (tid < 64) *(float4*)&sbias[tid*4] = *(const float4*)(bias + tid*4);

  {
    const int row_local = tid >> 1;
    const int half = tid & 1;
    const int b = row_local >> 4, nl = row_local & 15;
    const float* src = X + (size_t)(b*cNQ + n0 + nl)*256 + half*128;
    u16* dstrow = sA + row_local*256;
    #pragma unroll
    for (int u = 0; u < 16; ++u) {
      int s = half*16 + u;
      float4 v0 = *(const float4*)(src + u*8);
      float4 v1 = *(const float4*)(src + u*8 + 4);
      u16 tmp[8] = {f2bf(v0.x),f2bf(v0.y),f2bf(v0.z),f2bf(v0.w),
                    f2bf(v1.x),f2bf(v1.y),f2bf(v1.z),f2bf(v1.w)};
      int p = (s & ~7) | ((s & 7) ^ (row_local & 7));
      *(bf16x8*)(dstrow + p*8) = *(bf16x8*)tmp;
    }
  }
  __syncthreads();

  bf16x8 af[2][8];
  #pragma unroll
  for (int rf = 0; rf < 2; ++rf) {
    const int row_a = 32*w + 16*rf + lh;
    #pragma unroll
    for (int kg = 0; kg < 8; ++kg) {
      int p = (kg >> 1)*8 + (((kg & 1)*4 + lq) ^ (row_a & 7));
      af[rf][kg] = *(const bf16x8*)(sA + row_a*256 + p*8);
    }
  }

  f32x4 acc[2][16];
  #pragma unroll
  for (int rf = 0; rf < 2; ++rf)
    #pragma unroll
    for (int cf = 0; cf < 16; ++cf) acc[rf][cf] = (f32x4){0,0,0,0};

  for (int st = 0; st < 4; ++st) {
    __syncthreads();
    stageB(WT, st, sB, tid);
    __syncthreads();
    #pragma unroll
    for (int kk2 = 0; kk2 < 2; ++kk2) {
      const int kg = st*2 + kk2;
      #pragma unroll
      for (int cf = 0; cf < 16; ++cf) {
        const int n = 16*cf + lh;
        bf16x8 bf = *(const bf16x8*)(sB + n*64 + (((kk2*4 + lq) ^ (n & 7)))*8);
        acc[0][cf] = __builtin_amdgcn_mfma_f32_16x16x32_bf16(af[0][kg], bf, acc[0][cf], 0,0,0);
        acc[1][cf] = __builtin_amdgcn_mfma_f32_16x16x32_bf16(af[1][kg], bf, acc[1][cf], 0,0,0);
      }
    }
  }

  __syncthreads();
  #pragma unroll
  for (int rf = 0; rf < 2; ++rf)
    #pragma unroll
    for (int cf = 0; cf < 16; ++cf) {
      const int col = 16*cf + lh;
      #pragma unroll
      for (int i = 0; i < 4; ++i) {
        int row_local = 32*w + 16*rf + 4*lq + i;
        sC[row_local*256 + col] = acc[rf][cf][i] + sbias[col];
      }
    }
  __syncthreads();

  #pragma unroll
  for (int jj = 0; jj < 16; ++jj) {
    int id = tid + jj*128;
    int nl = id >> 7, m = id & 127;
    int n = n0 + nl;
    float tc = (m < 64) ? (float)(n & 63) : (float)(n >> 6);
    float sn, cs;
    __sincosf(tc * sfreq[m & 63], &sn, &cs);
    #pragma unroll
    for (int b = 0; b < 4; ++b) {
      float2 x = *(const float2*)&sC[(b*16 + nl)*256 + 2*m];
      float ox = (x.x*cs - x.y*sn) * cSCALE;
      float oy = (x.x*sn + x.y*cs) * cSCALE;
      unsigned u = (unsigned)f2bf(ox) | ((unsigned)f2bf(oy) << 16);
      *(unsigned*)(Y + (size_t)(b*cNQ + n + 0)*256 + 2*m) = u;
    }
  }
}

// ---------------------------------------------------------------------------
// kv_fused: kvk (blocks 0..895) | kvv (896..1119) | tail (1120..1183).
// ---------------------------------------------------------------------------
__global__ __launch_bounds__(TPB) void kv_fused(
    const float* __restrict__ kin, const float* __restrict__ vin,
    const u16* __restrict__ WkT, const u16* __restrict__ WvT,
    const float* __restrict__ Wk, const float* __restrict__ bk_,
    const float* __restrict__ Wv, const float* __restrict__ bv_,
    u16* __restrict__ klm, u16* __restrict__ vlmT)
{
  __shared__ u16 sA[128*64];     // 16 KB
  __shared__ u16 sB[256*64];     // 32 KB
  __shared__ float sf0[256];     // bias
  __shared__ float sf1[64];      // freqs

  const int tid  = threadIdx.x;
  const int lane = tid & 63;
  const int w    = tid >> 6;
  const int lh   = lane & 15;
  const int lq   = lane >> 4;
  const int bid  = blockIdx.x;

  if (bid < cB*224) {
    // ---------------- kvk branch ----------------
    const int b    = bid / 224;
    const int t    = bid % 224;
    const int row0 = t * 128;
    const int ty0  = (t & 31) * 2;

    if (tid < 64) {
      sf1[tid] = __expf(-(float)tid * cLOGTH);
      *(float4*)&sf0[tid*4] = *(const float4*)(bk_ + tid*4);
    }

    stageW64(WkT, sB, tid);

    {
      const int row = tid >> 1, half = tid & 1;
      const float* src = kin + ((size_t)b*cNK + row0 + row)*cKV + half*32;
      u16 tmp[32];
      #pragma unroll
      for (int u = 0; u < 8; ++u) {
        float4 v = *(const float4*)(src + u*4);
        tmp[u*4+0]=f2bf(v.x); tmp[u*4+1]=f2bf(v.y); tmp[u*4+2]=f2bf(v.z); tmp[u*4+3]=f2bf(v.w);
      }
      #pragma unroll
      for (int s4 = 0; s4 < 4; ++s4) {
        int s = half*4 + s4;
        int p = s ^ (row & 7);
        *(bf16x8*)(sA + row*64 + p*8) = *(bf16x8*)&tmp[s4*8];
      }
    }
    __syncthreads();

    f32x4 acc[2][16];
    #pragma unroll
    for (int rf = 0; rf < 2; ++rf)
      #pragma unroll
      for (int cf = 0; cf < 16; ++cf) acc[rf][cf] = (f32x4){0,0,0,0};

    #pragma unroll
    for (int kk2 = 0; kk2 < 2; ++kk2) {
      bf16x8 af[2];
      #pragma unroll
      for (int rf = 0; rf < 2; ++rf) {
        const int row_a = 64*rf + 16*w + lh;
        int p = (kk2*4 + lq) ^ (row_a & 7);
        af[rf] = *(const bf16x8*)(sA + row_a*64 + p*8);
      }
      #pragma unroll
      for (int cf = 0; cf < 16; ++cf) {
        const int n = 16*cf + lh;
        bf16x8 bf = *(const bf16x8*)(sB + n*64 + ((kk2*4 + lq) ^ (n & 7))*8);
        acc[0][cf] = __builtin_amdgcn_mfma_f32_16x16x32_bf16(af[0], bf, acc[0][cf], 0,0,0);
        acc[1][cf] = __builtin_amdgcn_mfma_f32_16x16x32_bf16(af[1], bf, acc[1][cf], 0,0,0);
      }
    }

    const int tx_base = 16*w + 4*lq;
    const int l_base  = 32*t + 8*w + 2*lq;
    #pragma unroll
    for (int cf = 0; cf < 16; ++cf) {
      const int c  = 16*cf + lh;
      const float fr = sf1[(c >> 1) & 63];
      const float bb = sf0[c];
      float outp[2][4];
      if (cf < 8) {
        float snv[4], csv[4];
        #pragma unroll
        for (int i = 0; i < 4; ++i)
          __sincosf((float)(tx_base + i) * fr, &snv[i], &csv[i]);
        #pragma unroll
        for (int rf = 0; rf < 2; ++rf)
          #pragma unroll
          for (int i = 0; i < 4; ++i) {
            float v = acc[rf][cf][i] + bb;
            float pr = dpp_mov<0xB1>(v);
            outp[rf][i] = (lh & 1) ? (pr*snv[i] + v*csv[i]) : (v*csv[i] - pr*snv[i]);
          }
      } else {
        #pragma unroll
        for (int rf = 0; rf < 2; ++rf) {
          float sn, cs;
          __sincosf((float)(ty0 + rf) * fr, &sn, &cs);
          #pragma unroll
          for (int i = 0; i < 4; ++i) {
            float v = acc[rf][cf][i] + bb;
            float pr = dpp_mov<0xB1>(v);
            outp[rf][i] = (lh & 1) ? (pr*sn + v*cs) : (v*cs - pr*sn);
          }
        }
      }
      float o0 = (outp[0][0] + outp[0][1] + outp[1][0] + outp[1][1]) * 0.25f + cKOFF;
      float o1 = (outp[0][2] + outp[0][3] + outp[1][2] + outp[1][3]) * 0.25f + cKOFF;
      const int sl0 = (c >> 3) ^ (l_base & 7);
      const int sl1 = (c >> 3) ^ ((l_base + 1) & 7);
      klm[((size_t)b*cNLM + l_base    )*256 + sl0*8 + (c & 7)] = f2bf(o0);
      klm[((size_t)b*cNLM + l_base + 1)*256 + sl1*8 + (c & 7)] = f2bf(o1);
    }

  } else if (bid < cB*224 + cB*56) {
    // ---------------- kvv branch ----------------
    const int idx = bid - cB*224;
    const int b   = idx / 56;
    const int l0  = (idx % 56) * 128;

    if (tid < 64) *(float4*)&sf0[tid*4] = *(const float4*)(bv_ + tid*4);

    stageW64(WvT, sB, tid);

    {
      const int row = tid >> 1, half = tid & 1;
      const int lm = l0 + row;
      const int f = lm >> 10, idx2 = lm & 1023;
      const int p_ = idx2 >> 5, q_ = idx2 & 31;
      const size_t r0 = (size_t)b*cNK + f*4096 + (2*p_)*64 + 2*q_;
      const float* s0 = vin + r0*cKV + half*32;
      u16 tmp[32];
      #pragma unroll
      for (int u = 0; u < 8; ++u) {
        float4 a = *(const float4*)(s0 + u*4);
        float4 a1 = *(const float4*)(s0 + 64 + u*4);
        float4 a2 = *(const float4*)(s0 + 64*64 + u*4);
        float4 a3 = *(const float4*)(s0 + 65*64 + u*4);
        tmp[u*4+0] = f2bf((a.x + a1.x + a2.x + a3.x) * 0.25f);
        tmp[u*4+1] = f2bf((a.y + a1.y + a2.y + a3.y) * 0.25f);
        tmp[u*4+2] = f2bf((a.z + a1.z + a2.z + a3.z) * 0.25f);
        tmp[u*4+3] = f2bf((a.w + a1.w + a2.w + a3.w) * 0.25f);
      }
      #pragma unroll
      for (int s4 = 0; s4 < 4; ++s4) {
        int s = half*4 + s4;
        int p = s ^ (row & 7);
        *(bf16x8*)(sA + row*64 + p*8) = *(bf16x8*)&tmp[s4*8];
      }
    }
    __syncthreads();

    f32x4 acc[2][16];
    #pragma unroll
    for (int rf = 0; rf < 2; ++rf)
      #pragma unroll
      for (int cf = 0; cf < 16; ++cf) acc[rf][cf] = (f32x4){0,0,0,0};

    #pragma unroll
    for (int kk2 = 0; kk2 < 2; ++kk2) {
      bf16x8 af[2];
      #pragma unroll
      for (int rf = 0; rf < 2; ++rf) {
        const int row_a = 32*w + 16*rf + lh;
        int p = (kk2*4 + lq) ^ (row_a & 7);
        af[rf] = *(const bf16x8*)(sA + row_a*64 + p*8);
      }
      #pragma unroll
      for (int cf = 0; cf < 16; ++cf) {
        const int n = 16*cf + lh;
        bf16x8 bf = *(const bf16x8*)(sB + n*64 + ((kk2*4 + lq) ^ (n & 7))*8);
        acc[0][cf] = __builtin_amdgcn_mfma_f32_16x16x32_bf16(af[0], bf, acc[0][cf], 0,0,0);
        acc[1][cf] = __builtin_amdgcn_mfma_f32_16x16x32_bf16(af[1], bf, acc[1][cf], 0,0,0);
      }
    }

    #pragma unroll
    for (int rf = 0; rf < 2; ++rf) {
      const int key0 = l0 + 32*w + 16*rf + 4*lq;
      #pragma unroll
      for (int cf = 0; cf < 16; ++cf) {
        const int c = 16*cf + lh;
        const float bb = sf0[c];
        ushort4 o;
        o.x = f2bf(acc[rf][cf][0] + bb);
        o.y = f2bf(acc[rf][cf][1] + bb);
        o.z = f2bf(acc[rf][cf][2] + bb);
        o.w = f2bf(acc[rf][cf][3] + bb);
        *(ushort4*)(vlmT + ((size_t)b*256 + c)*cNLM + key0) = o;
      }
    }

  } else {
    // ---------------- tail branch ----------------
    const int idx = bid - (cB*224 + cB*56);
    const int b   = idx >> 4;
    const int l0  = cNPOOL + (idx & 15) * 4;

    float* skf = (float*)sA;            // [4][68]
    float* svf = (float*)sA + 4*68;     // [4][68]

    if (tid < 64) {
      int r = tid >> 4, c4 = tid & 15;
      const size_t off = ((size_t)b*cNK + cNKR + (l0 - cNPOOL) + r)*cKV + c4*4;
      *(float4*)&skf[r*68 + c4*4] = *(const float4*)(kin + off);
      *(float4*)&svf[r*68 + c4*4] = *(const float4*)(vin + off);
    }
    __syncthreads();

    const int c0 = (tid & 63) * 4;
    const int rg = tid >> 6;
    const float4 bbk = *(const float4*)(bk_ + c0);
    const float4 bbv = *(const float4*)(bv_ + c0);

    float4 ak = {0,0,0,0}, av = {0,0,0,0};
    for (int i = 0; i < 64; i += 4) {
      const float4 k0w = *(const float4*)(Wk + (size_t)(i+0)*256 + c0);
      const float4 k1w = *(const float4*)(Wk + (size_t)(i+1)*256 + c0);
      const float4 k2w = *(const float4*)(Wk + (size_t)(i+2)*256 + c0);
      const float4 k3w = *(const float4*)(Wk + (size_t)(i+3)*256 + c0);
      const float4 v0w = *(const float4*)(Wv + (size_t)(i+0)*256 + c0);
      const float4 v1w = *(const float4*)(Wv + (size_t)(i+1)*256 + c0);
      const float4 v2w = *(const float4*)(Wv + (size_t)(i+2)*256 + c0);
      const float4 v3w = *(const float4*)(Wv + (size_t)(i+3)*256 + c0);
      mac4(ak, *(const float4*)&skf[rg*68 + i], k0w,k1w,k2w,k3w);
      mac4(av, *(const float4*)&svf[rg*68 + i], v0w,v1w,v2w,v3w);
    }
    ak.x += bbk.x; ak.y += bbk.y; ak.z += bbk.z; ak.w += bbk.w;
    av.x += bbv.x; av.y += bbv.y; av.z += bbv.z; av.w += bbv.w;

    const int key = l0 + rg;
    {
      int slot = (c0 >> 3) ^ (key & 7);
      u16* dst = klm + (size_t)(b*cNLM + key)*256 + slot*8 + (c0 & 7);
      ushort4 w4; w4.x = f2bf(ak.x); w4.y = f2bf(ak.y); w4.z = f2bf(ak.z); w4.w = f2bf(ak.w);
      *(ushort4*)dst = w4;
    }
    vlmT[(size_t)(b*256 + c0+0)*cNLM + key] = f2bf(av.x);
    vlmT[(size_t)(b*256 + c0+1)*cNLM + key] = f2bf(av.y);
    vlmT[(size_t)(b*256 + c0+2)*cNLM + key] = f2bf(av.z);
    vlmT[(size_t)(b*256 + c0+3)*cNLM + key] = f2bf(av.w);
  }
}

// ---------------------------------------------------------------------------
// MFMA flash attention (R4 structure; R12: stage_tile issued BEFORE the QK
// MFMA cluster — loads get the full tile span of latency cover before the
// end-of-tile barrier drain. Legal: stage writes buf[cur^1], reads are from
// buf[cur]; previous barrier guarantees buf[cur^1] readers are done).
// ---------------------------------------------------------------------------
__device__ __forceinline__ void stage_tile(int b, int kt0, int w, int lane,
    u16* sKbuf, u16* sVbuf, const u16* __restrict__ klm, const u16* __restrict__ vlmT)
{
  {
    const u16* g = klm + ((size_t)(b*cNLM + kt0 + 8*w))*256 + lane*8;
    u16* l = sKbuf + 8*w*256;
    #pragma unroll
    for (int i = 0; i < 4; ++i)
      gl_lds16(g + i*512, l + i*512);
  }
  {
    const u16* g = vlmT + ((size_t)(b*256 + 64*w + (lane>>2)))*cNLM + kt0 + (lane&3)*8;
    u16* l = sVbuf + 64*w*32;
    #pragma unroll
    for (int i = 0; i < 4; ++i)
      gl_lds16(g + (size_t)16*i*cNLM, l + i*512);
  }
}

__global__ __launch_bounds__(TPB, 2) void attn_kernel(
    const u16* __restrict__ qr, const u16* __restrict__ klm,
    const u16* __restrict__ vlmT, u16* __restrict__ Opart, float2* __restrict__ ml)
{
  __shared__ u16 sK[2][32*256];
  __shared__ u16 sV[2][256*32];
  __shared__ unsigned sP[4][32*16];

  const int tid  = threadIdx.x;
  const int lane = tid & 63;
  const int w    = tid >> 6;
  const int lh   = lane & 15;
  const int lq   = lane >> 4;

  const int bx    = blockIdx.x;
  const int split = bx & 3;
  const int qb    = (bx >> 2) & 31;
  const int b     = bx >> 7;

  const int ts0 = split*56 + (split < 2 ? split : 2);
  const int len = 56 + (split < 2 ? 1 : 0);
  const int qw  = qb*cQT + 32*w;

  bf16x8 qf[2][8];
  {
    const u16* qbase = qr + (size_t)(b*cNQ + qw + lh)*256 + lq*8;
    #pragma unroll
    for (int rf = 0; rf < 2; ++rf)
      #pragma unroll
      for (int kk = 0; kk < 8; ++kk)
        qf[rf][kk] = *(const bf16x8*)(qbase + (size_t)rf*16*256 + kk*32);
  }

  bf16x8 onesf;
  #pragma unroll
  for (int j = 0; j < 8; ++j) onesf[j] = (short)0x3F80;

  f32x4 O[2][16];
  #pragma unroll
  for (int rf = 0; rf < 2; ++rf)
    #pragma unroll
    for (int cf = 0; cf < 16; ++cf)
      O[rf][cf] = (f32x4){0.f,0.f,0.f,0.f};

  f32x4 lacc[2];
  lacc[0] = (f32x4){0,0,0,0}; lacc[1] = (f32x4){0,0,0,0};
  float m_[2][4];
  #pragma unroll
  for (int rf = 0; rf < 2; ++rf)
    #pragma unroll
    for (int i = 0; i < 4; ++i) m_[rf][i] = -INFINITY;

  stage_tile(b, ts0*cKT, w, lane, sK[0], sV[0], klm, vlmT);
  __syncthreads();

  int cur = 0;
  for (int t = 0; t < len; ++t) {
    // issue next-tile loads EARLY (before QK) — T14 issue-early
    if (t+1 < len) stage_tile(b, (ts0+t+1)*cKT, w, lane, sK[cur^1], sV[cur^1], klm, vlmT);

    f32x4 S[2][2];
    S[0][0] = (f32x4){0,0,0,0}; S[0][1] = (f32x4){0,0,0,0};
    S[1][0] = (f32x4){0,0,0,0}; S[1][1] = (f32x4){0,0,0,0};
    __builtin_amdgcn_s_setprio(1);
    #pragma unroll
    for (int kk = 0; kk < 8; ++kk) {
      #pragma unroll
      for (int cf = 0; cf < 2; ++cf) {
        const int r = 16*cf + lh;
        const int slot = (4*kk + lq) ^ (r & 7);
        bf16x8 kf = *(const bf16x8*)(sK[cur] + r*256 + slot*8);
        S[0][cf] = __builtin_amdgcn_mfma_f32_16x16x32_bf16(qf[0][kk], kf, S[0][cf], 0,0,0);
        S[1][cf] = __builtin_amdgcn_mfma_f32_16x16x32_bf16(qf[1][kk], kf, S[1][cf], 0,0,0);
      }
    }
    __builtin_amdgcn_s_setprio(0);

    bool need = false;
    #pragma unroll
    for (int rf = 0; rf < 2; ++rf)
      #pragma unroll
      for (int cf = 0; cf < 2; ++cf)
        #pragma unroll
        for (int i = 0; i < 4; ++i)
          need |= (S[rf][cf][i] > m_[rf][i] + cTHR);

    if (__ballot(need)) {   // rare: recompute max, rescale O and l
      #pragma unroll
      for (int rf = 0; rf < 2; ++rf) {
        float al[4];
        #pragma unroll
        for (int i = 0; i < 4; ++i) {
          float tm = redmax16(fmaxf(S[rf][0][i], S[rf][1][i]));
          float mn = fmaxf(m_[rf][i], tm);
          al[i] = __expf(m_[rf][i] - mn);
          m_[rf][i] = mn;
          lacc[rf][i] *= al[i];
        }
        #pragma unroll
        for (int cf = 0; cf < 16; ++cf) {
          O[rf][cf][0] *= al[0]; O[rf][cf][1] *= al[1];
          O[rf][cf][2] *= al[2]; O[rf][cf][3] *= al[3];
        }
      }
    }

    // p = exp(S - m), pack to bf16 -> wave-private sP
    #pragma unroll
    for (int rf = 0; rf < 2; ++rf) {
      f32x4 p0, p1;
      #pragma unroll
      for (int i = 0; i < 4; ++i) {
        p0[i] = __expf(S[rf][0][i] - m_[rf][i]);
        p1[i] = __expf(S[rf][1][i] - m_[rf][i]);
      }
      #pragma unroll
      for (int cf = 0; cf < 2; ++cf) {
        #pragma unroll
        for (int i = 0; i < 4; ++i) {
          float pv = cf ? p1[i] : p0[i];
          float other = dpp_mov<0xB1>(pv);
          if (!(lane & 1)) {
            unsigned u = (unsigned)f2bf(pv) | ((unsigned)f2bf(other) << 16);
            sP[w][(16*rf + 4*lq + i)*16 + (lh >> 1) + 8*cf] = u;
          }
        }
      }
    }

    const u16* sPw = (const u16*)sP[w];
    bf16x8 pa0 = *(const bf16x8*)(sPw + lh*32 + lq*8);
    bf16x8 pa1 = *(const bf16x8*)(sPw + (16 + lh)*32 + lq*8);
    __builtin_amdgcn_s_setprio(1);
    lacc[0] = __builtin_amdgcn_mfma_f32_16x16x32_bf16(pa0, onesf, lacc[0], 0,0,0);
    lacc[1] = __builtin_amdgcn_mfma_f32_16x16x32_bf16(pa1, onesf, lacc[1], 0,0,0);
    #pragma unroll
    for (int cf = 0; cf < 16; ++cf) {
      bf16x8 vf = *(const bf16x8*)(sV[cur] + (16*cf + lh)*32 + lq*8);
      O[0][cf] = __builtin_amdgcn_mfma_f32_16x16x32_bf16(pa0, vf, O[0][cf], 0,0,0);
      O[1][cf] = __builtin_amdgcn_mfma_f32_16x16x32_bf16(pa1, vf, O[1][cf], 0,0,0);
    }
    __builtin_amdgcn_s_setprio(0);

    __syncthreads();
    cur ^= 1;
  }

  const size_t obase = (size_t)split*(cB*cNQ) + (size_t)b*cNQ;
  #pragma unroll
  for (int rf = 0; rf < 2; ++rf)
    #pragma unroll
    for (int cf = 0; cf < 16; ++cf) {
      #pragma unroll
      for (int i = 0; i < 4; ++i) {
        int row = qw + 16*rf + 4*lq + i;
        Opart[(obase + row)*256 + 16*cf + lh] = f2bf(O[rf][cf][i]);
      }
    }
  if (lh == 0) {
    #pragma unroll
    for (int rf = 0; rf < 2; ++rf)
      #pragma unroll
      for (int i = 0; i < 4; ++i) {
        int row = qw + 16*rf + 4*lq + i;
        ml[obase + row] = make_float2(m_[rf][i], lacc[rf][i]);
      }
  }
}

// ---------------------------------------------------------------------------
// projo_mfma (FUSED combine): out = combine(Opart, ml) @ Wo + bo.
// ---------------------------------------------------------------------------
__global__ __launch_bounds__(128) void projo_mfma(
    const u16* __restrict__ Opart, const float2* __restrict__ ml,
    const u16* __restrict__ WThi, const u16* __restrict__ WTlo,
    const float* __restrict__ bias, float* __restrict__ Y)
{
  __shared__ u16 lds[49152];
  u16* sAhi = lds;
  u16* sAlo = lds + 16384;
  u16* sB   = lds + 32768;
  __shared__ float sbo[256];
  __shared__ float sWt[64][4];
  __shared__ float sInv[64];

  const int tid  = threadIdx.x;
  const int lane = tid & 63;
  const int w    = tid >> 6;
  const int lh   = lane & 15;
  const int lq   = lane >> 4;
  const int row0 = blockIdx.x * 64;

  if (tid < 64) *(float4*)&sbo[tid*4] = *(const float4*)(bias + tid*4);

  if (tid < 64) {
    const int R = row0 + tid;
    float2 mlv[cKSPLIT];
    float M = -INFINITY;
    #pragma unroll
    for (int s = 0; s < cKSPLIT; ++s) {
      mlv[s] = ml[(size_t)s*(cB*cNQ) + R];
      M = fmaxf(M, mlv[s].x);
    }
    float L = 0.f;
    #pragma unroll
    for (int s = 0; s < cKSPLIT; ++s) {
      float wg = __expf(mlv[s].x - M);
      sWt[tid][s] = wg;
      L += wg * mlv[s].y;
    }
    sInv[tid] = 1.f / L;
  }
  __syncthreads();

  {
    const int rl = tid >> 6;
    const int c0 = (tid & 63) * 4;
    const int s4 = c0 >> 3;
    #pragma unroll 4
    for (int rr = 0; rr < 64; rr += 2) {
      const int r = rr + rl;
      const int R = row0 + r;
      const float w0 = sWt[r][0], w1 = sWt[r][1], w2 = sWt[r][2], w3 = sWt[r][3];
      const float iv = sInv[r];
      const ushort4 q0 = *(const ushort4*)(Opart + ((size_t)0*(cB*cNQ) + R)*256 + c0);
      const ushort4 q1 = *(const ushort4*)(Opart + ((size_t)1*(cB*cNQ) + R)*256 + c0);
      const ushort4 q2 = *(const ushort4*)(Opart + ((size_t)2*(cB*cNQ) + R)*256 + c0);
      const ushort4 q3 = *(const ushort4*)(Opart + ((size_t)3*(cB*cNQ) + R)*256 + c0);
      float xv[4];
      xv[0] = (w0*bf2f(q0.x) + w1*bf2f(q1.x) + w2*bf2f(q2.x) + w3*bf2f(q3.x)) * iv;
      xv[1] = (w0*bf2f(q0.y) + w1*bf2f(q1.y) + w2*bf2f(q2.y) + w3*bf2f(q3.y)) * iv;
      xv[2] = (w0*bf2f(q0.z) + w1*bf2f(q1.z) + w2*bf2f(q2.z) + w3*bf2f(q3.z)) * iv;
      xv[3] = (w0*bf2f(q0.w) + w1*bf2f(q1.w) + w2*bf2f(q2.w) + w3*bf2f(q3.w)) * iv;
      ushort4 h, l;
      #pragma unroll
      for (int j = 0; j < 4; ++j) {
        u16 hb = f2bf(xv[j]);
        u16 lb = f2bf(xv[j] - bf2f(hb));
        ((u16*)&h)[j] = hb; ((u16*)&l)[j] = lb;
      }
      const int p = (s4 & ~7) | ((s4 & 7) ^ (r & 7));
      const int off = r*256 + p*8 + (c0 & 4);
      *(ushort4*)(sAhi + off) = h;
      *(ushort4*)(sAlo + off) = l;
    }
  }

  f32x4 acc[2][16];
  #pragma unroll
  for (int rf = 0; rf < 2; ++rf)
    #pragma unroll
    for (int cf = 0; cf < 16; ++cf) acc[rf][cf] = (f32x4){0,0,0,0};

  __syncthreads();

  for (int st = 0; st < 4; ++st) {
    __syncthreads();
    stageB(WThi, st, sB, tid);
    __syncthreads();
    #pragma unroll
    for (int kk2 = 0; kk2 < 2; ++kk2) {
      bf16x8 ah[2], al[2];
      #pragma unroll
      for (int rf = 0; rf < 2; ++rf) {
        const int row_a = 32*w + 16*rf + lh;
        int p = st*8 + ((kk2*4 + lq) ^ (row_a & 7));
        ah[rf] = *(const bf16x8*)(sAhi + row_a*256 + p*8);
        al[rf] = *(const bf16x8*)(sAlo + row_a*256 + p*8);
      }
      #pragma unroll
      for (int cf = 0; cf < 16; ++cf) {
        const int n = 16*cf + lh;
        bf16x8 bf = *(const bf16x8*)(sB + n*64 + (((kk2*4 + lq) ^ (n & 7)))*8);
        #pragma unroll
        for (int rf = 0; rf < 2; ++rf) {
          acc[rf][cf] = __builtin_amdgcn_mfma_f32_16x16x32_bf16(ah[rf], bf, acc[rf][cf], 0,0,0);
          acc[rf][cf] = __builtin_amdgcn_mfma_f32_16x16x32_bf16(al[rf], bf, acc[rf][cf], 0,0,0);
        }
      }
    }
  }
  for (int st = 0; st < 4; ++st) {
    __syncthreads();
    stageB(WTlo, st, sB, tid);
    __syncthreads();
    #pragma unroll
    for (int kk2 = 0; kk2 < 2; ++kk2) {
      bf16x8 ah[2];
      #pragma unroll
      for (int rf = 0; rf < 2; ++rf) {
        const int row_a = 32*w + 16*rf + lh;
        int p = st*8 + ((kk2*4 + lq) ^ (row_a & 7));
        ah[rf] = *(const bf16x8*)(sAhi + row_a*256 + p*8);
      }
      #pragma unroll
      for (int cf = 0; cf < 16; ++cf) {
        const int n = 16*cf + lh;
        bf16x8 bf = *(const bf16x8*)(sB + n*64 + (((kk2*4 + lq) ^ (n & 7)))*8);
        #pragma unroll
        for (int rf = 0; rf < 2; ++rf)
          acc[rf][cf] = __builtin_amdgcn_mfma_f32_16x16x32_bf16(ah[rf], bf, acc[rf][cf], 0,0,0);
      }
    }
  }

  #pragma unroll
  for (int rf = 0; rf < 2; ++rf)
    #pragma unroll
    for (int cf = 0; cf < 16; ++cf) {
      const int col = 16*cf + lh;
      #pragma unroll
      for (int i = 0; i < 4; ++i) {
        int row = row0 + 32*w + 16*rf + 4*lq + i;
        Y[(size_t)row*256 + col] = acc[rf][cf][i] + sbo[col];
      }
    }
}

// ---------------------------------------------------------------------------
extern "C" void kernel_launch(void* const* d_in, const int* in_sizes, int n_in,
                              void* d_out, int out_size, void* d_ws, size_t ws_size,
                              hipStream_t stream)
{
  const float* q  = (const float*)d_in[0];
  const float* k  = (const float*)d_in[1];
  const float* v  = (const float*)d_in[2];
  const float* Wq = (const float*)d_in[3];
  const float* bq = (const float*)d_in[4];
  const float* Wk = (const float*)d_in[5];
  const float* bk = (const float*)d_in[6];
  const float* Wv = (const float*)d_in[7];
  const float* bv = (const float*)d_in[8];
  const float* Wo = (const float*)d_in[9];
  const float* bo = (const float*)d_in[10];
  float* out = (float*)d_out;

  constexpr size_t qrB    = (size_t)cB*cNQ*256*sizeof(u16);        //  8.39 MB
  constexpr size_t klmB   = (size_t)cB*cNLM*256*sizeof(u16);       // 14.81 MB
  constexpr size_t vlmB   = klmB;
  constexpr size_t opartB = (size_t)cKSPLIT*cB*cNQ*256*sizeof(u16);// 33.55 MB
  constexpr size_t mlB    = (size_t)cKSPLIT*cB*cNQ*sizeof(float2); //  0.52 MB

  char* w8 = (char*)d_ws;
  u16*    qr    = (u16*)(w8);
  u16*    klm   = (u16*)(w8 + qrB);
  u16*    vlmT  = (u16*)(w8 + qrB + klmB);
  u16*    Opart = (u16*)(w8 + qrB + klmB + vlmB);
  float2* mlp   = (float2*)(w8 + qrB + klmB + vlmB + opartB);
  u16*    WqT   = (u16*)(w8 + qrB + klmB + vlmB + opartB + mlB);
  u16*    WoThi = WqT   + 256*256;
  u16*    WoTlo = WoThi + 256*256;
  u16*    WkT   = WoTlo + 256*256;
  u16*    WvT   = WkT   + 256*64;

  wprep_kernel<<<160, TPB, 0, stream>>>(Wq, Wo, Wk, Wv, WqT, WoThi, WoTlo, WkT, WvT);
  projq_mfma  <<<cNQ/16, 128, 0, stream>>>(q, WqT, bq, qr);
  kv_fused    <<<cB*224 + cB*56 + cB*16, TPB, 0, stream>>>(
                  k, v, WkT, WvT, Wk, bk, Wv, bv, klm, vlmT);
  attn_kernel <<<cB*(cNQ/cQT)*cKSPLIT, TPB, 0, stream>>>(qr, klm, vlmT, Opart, mlp);
  projo_mfma  <<<(cB*cNQ)/64, 128, 0, stream>>>(Opart, mlp, WoThi, WoTlo, bo, out);
}

// Round 13
// 240.123 us; speedup vs baseline: 1.0742x; 1.0742x over previous
//
#include <hip/hip_runtime.h>
#include <hip/hip_bf16.h>
#include <math.h>

#define TPB 256

typedef unsigned short u16;
typedef __attribute__((ext_vector_type(8))) short bf16x8;
typedef __attribute__((ext_vector_type(4))) float f32x4;

constexpr int cB    = 4;
constexpr int cNQ   = 4096;
constexpr int cKV   = 64;
constexpr int cNK   = 28736;
constexpr int cNKR  = 28672;
constexpr int cNLM  = 7232;   // 7*1024 + 64
constexpr int cNPOOL= 7168;
constexpr int cKT   = 32;
constexpr int cKSPLIT = 4;
constexpr int cQT   = 128;
constexpr float cSCALE  = 0.0625f;                 // 1/sqrt(256)
constexpr float cLOGTH  = 0.14391156831212787f;    // ln(10000)/64
constexpr float cKOFF   = 1.3862943611198906f;     // 2*ln(2)
constexpr float cTHR    = 8.0f;                    // defer-max threshold

// ---------------- helpers ----------------
__device__ __forceinline__ u16 f2bf(float x) {
  __hip_bfloat16 h = __float2bfloat16(x);
  return __builtin_bit_cast(u16, h);
}
__device__ __forceinline__ float bf2f(u16 u) {
  return __builtin_bit_cast(float, ((unsigned)u) << 16);
}

template<int CTRL>
__device__ __forceinline__ float dpp_mov(float v) {
  return __builtin_bit_cast(float,
      __builtin_amdgcn_update_dpp(0, __builtin_bit_cast(int, v), CTRL, 0xf, 0xf, true));
}
__device__ __forceinline__ float redmax16(float v) {
  v = fmaxf(v, dpp_mov<0x128>(v));
  v = fmaxf(v, dpp_mov<0x124>(v));
  v = fmaxf(v, dpp_mov<0x122>(v));
  v = fmaxf(v, dpp_mov<0x121>(v));
  return v;
}

__device__ __forceinline__ void gl_lds16(const u16* g, u16* l) {
  __builtin_amdgcn_global_load_lds(
      (const __attribute__((address_space(1))) unsigned int*)g,
      (__attribute__((address_space(3))) unsigned int*)l, 16, 0, 0);
}

__device__ __forceinline__ void mac4(float4& a, const float4 x,
    const float4 w0, const float4 w1, const float4 w2, const float4 w3) {
  a.x = fmaf(x.x,w0.x, fmaf(x.y,w1.x, fmaf(x.z,w2.x, fmaf(x.w,w3.x, a.x))));
  a.y = fmaf(x.x,w0.y, fmaf(x.y,w1.y, fmaf(x.z,w2.y, fmaf(x.w,w3.y, a.y))));
  a.z = fmaf(x.x,w0.z, fmaf(x.y,w1.z, fmaf(x.z,w2.z, fmaf(x.w,w3.z, a.z))));
  a.w = fmaf(x.x,w0.w, fmaf(x.y,w1.w, fmaf(x.z,w2.w, fmaf(x.w,w3.w, a.w))));
}

// stage one 256n x 64k bf16 B-tile (pre-swizzled global) into LDS via global_load_lds
__device__ __forceinline__ void stageB(const u16* __restrict__ WT, int st, u16* sB, int tid) {
  #pragma unroll
  for (int r = 0; r < 16; ++r) {
    int cu = r*128 + (tid & ~63);
    int c  = r*128 + tid;
    gl_lds16(WT + (size_t)(c >> 3)*256 + (size_t)(st*8 + (c & 7))*8,
             sB + (size_t)cu*8);
  }
}

// stage a full 256n x 64k bf16 weight (pre-swizzled [n][64] global) into LDS
__device__ __forceinline__ void stageW64(const u16* __restrict__ WT, u16* sB, int tid) {
  #pragma unroll
  for (int r = 0; r < 8; ++r) {
    int idx = r*256 + tid;
    gl_lds16(WT + (size_t)idx*8, sB + (size_t)(r*256 + (tid & ~63))*8);
  }
}

// ---------------------------------------------------------------------------
// wprep: transpose+bf16-convert+pre-swizzle weights.
// ---------------------------------------------------------------------------
__global__ __launch_bounds__(TPB) void wprep_kernel(
    const float* __restrict__ Wq, const float* __restrict__ Wo,
    const float* __restrict__ Wk, const float* __restrict__ Wv,
    u16* __restrict__ WqT, u16* __restrict__ WoThi, u16* __restrict__ WoTlo,
    u16* __restrict__ WkT, u16* __restrict__ WvT)
{
  __shared__ float sT[32][36];
  const int tid = threadIdx.x;
  const int bidx = blockIdx.x;

  const float* W; int t_idx; bool small; bool isWo = false;
  u16 *out0 = nullptr, *out1 = nullptr;
  if (bidx < 64)       { W = Wq; t_idx = bidx;      small = false; out0 = WqT; }
  else if (bidx < 128) { W = Wo; t_idx = bidx-64;   small = false; isWo = true; out0 = WoThi; out1 = WoTlo; }
  else if (bidx < 144) { W = Wk; t_idx = bidx-128;  small = true;  out0 = WkT; }
  else                 { W = Wv; t_idx = bidx-144;  small = true;  out0 = WvT; }

  const int k0 = (t_idx >> 3) * 32;
  const int n0 = (t_idx & 7) * 32;

  {
    int r = tid >> 3, c4 = (tid & 7) * 4;
    *(float4*)&sT[r][c4] = *(const float4*)(W + (size_t)(k0 + r)*256 + n0 + c4);
  }
  __syncthreads();

  const int n  = n0 + (tid >> 3);
  const int kq = (tid & 7) * 4;
  float v[4];
  #pragma unroll
  for (int j = 0; j < 4; ++j) v[j] = sT[kq + j][tid >> 3];

  const int s = (k0 + kq) >> 3;
  const int p = small ? (s ^ (n & 7)) : ((s & ~7) | ((s & 7) ^ (n & 7)));
  const int rowlen = small ? 64 : 256;
  const size_t off = (size_t)n*rowlen + p*8 + (kq & 4);

  if (!isWo) {
    ushort4 h; h.x = f2bf(v[0]); h.y = f2bf(v[1]); h.z = f2bf(v[2]); h.w = f2bf(v[3]);
    *(ushort4*)(out0 + off) = h;
  } else {
    ushort4 h, l;
    #pragma unroll
    for (int j = 0; j < 4; ++j) {
      u16 hb = f2bf(v[j]);
      u16 lb = f2bf(v[j] - bf2f(hb));
      ((u16*)&h)[j] = hb; ((u16*)&l)[j] = lb;
    }
    *(ushort4*)(out0 + off) = h;
    *(ushort4*)(out1 + off) = l;
  }
}

// ---------------------------------------------------------------------------
// projq_mfma: qr = rope(q @ Wq + bq) * scale, bf16 out.
// ---------------------------------------------------------------------------
__global__ __launch_bounds__(128) void projq_mfma(
    const float* __restrict__ X, const u16* __restrict__ WT,
    const float* __restrict__ bias, u16* __restrict__ Y)
{
  __shared__ u16 lds[32768];        // 64KB: sA 32K | sB 32K ; C overlays both
  u16* sA = lds;
  u16* sB = lds + 16384;
  float* sC = (float*)lds;          // [64][256] f32
  __shared__ float sfreq[64];
  __shared__ float sbias[256];

  const int tid  = threadIdx.x;
  const int lane = tid & 63;
  const int w    = tid >> 6;
  const int lh   = lane & 15;
  const int lq   = lane >> 4;
  const int n0   = blockIdx.x * 16;

  if (tid < 64) sfreq[tid] = __expf(-(float)tid * cLOGTH);
  if (tid < 64) *(float4*)&sbias[tid*4] = *(const float4*)(bias + tid*4);

  {
    const int row_local = tid >> 1;
    const int half = tid & 1;
    const int b = row_local >> 4, nl = row_local & 15;
    const float* src = X + (size_t)(b*cNQ + n0 + nl)*256 + half*128;
    u16* dstrow = sA + row_local*256;
    #pragma unroll
    for (int u = 0; u < 16; ++u) {
      int s = half*16 + u;
      float4 v0 = *(const float4*)(src + u*8);
      float4 v1 = *(const float4*)(src + u*8 + 4);
      u16 tmp[8] = {f2bf(v0.x),f2bf(v0.y),f2bf(v0.z),f2bf(v0.w),
                    f2bf(v1.x),f2bf(v1.y),f2bf(v1.z),f2bf(v1.w)};
      int p = (s & ~7) | ((s & 7) ^ (row_local & 7));
      *(bf16x8*)(dstrow + p*8) = *(bf16x8*)tmp;
    }
  }
  __syncthreads();

  bf16x8 af[2][8];
  #pragma unroll
  for (int rf = 0; rf < 2; ++rf) {
    const int row_a = 32*w + 16*rf + lh;
    #pragma unroll
    for (int kg = 0; kg < 8; ++kg) {
      int p = (kg >> 1)*8 + (((kg & 1)*4 + lq) ^ (row_a & 7));
      af[rf][kg] = *(const bf16x8*)(sA + row_a*256 + p*8);
    }
  }

  f32x4 acc[2][16];
  #pragma unroll
  for (int rf = 0; rf < 2; ++rf)
    #pragma unroll
    for (int cf = 0; cf < 16; ++cf) acc[rf][cf] = (f32x4){0,0,0,0};

  for (int st = 0; st < 4; ++st) {
    __syncthreads();
    stageB(WT, st, sB, tid);
    __syncthreads();
    #pragma unroll
    for (int kk2 = 0; kk2 < 2; ++kk2) {
      const int kg = st*2 + kk2;
      #pragma unroll
      for (int cf = 0; cf < 16; ++cf) {
        const int n = 16*cf + lh;
        bf16x8 bf = *(const bf16x8*)(sB + n*64 + (((kk2*4 + lq) ^ (n & 7)))*8);
        acc[0][cf] = __builtin_amdgcn_mfma_f32_16x16x32_bf16(af[0][kg], bf, acc[0][cf], 0,0,0);
        acc[1][cf] = __builtin_amdgcn_mfma_f32_16x16x32_bf16(af[1][kg], bf, acc[1][cf], 0,0,0);
      }
    }
  }

  __syncthreads();
  #pragma unroll
  for (int rf = 0; rf < 2; ++rf)
    #pragma unroll
    for (int cf = 0; cf < 16; ++cf) {
      const int col = 16*cf + lh;
      #pragma unroll
      for (int i = 0; i < 4; ++i) {
        int row_local = 32*w + 16*rf + 4*lq + i;
        sC[row_local*256 + col] = acc[rf][cf][i] + sbias[col];
      }
    }
  __syncthreads();

  #pragma unroll
  for (int jj = 0; jj < 16; ++jj) {
    int id = tid + jj*128;
    int nl = id >> 7, m = id & 127;
    int n = n0 + nl;
    float tc = (m < 64) ? (float)(n & 63) : (float)(n >> 6);
    float sn, cs;
    __sincosf(tc * sfreq[m & 63], &sn, &cs);
    #pragma unroll
    for (int b = 0; b < 4; ++b) {
      float2 x = *(const float2*)&sC[(b*16 + nl)*256 + 2*m];
      float ox = (x.x*cs - x.y*sn) * cSCALE;
      float oy = (x.x*sn + x.y*cs) * cSCALE;
      unsigned u = (unsigned)f2bf(ox) | ((unsigned)f2bf(oy) << 16);
      *(unsigned*)(Y + (size_t)(b*cNQ + n + 0)*256 + 2*m) = u;
    }
  }
}

// ---------------------------------------------------------------------------
// kv_fused: kvk (blocks 0..895) | kvv (896..1119) | tail (1120..1183).
// ---------------------------------------------------------------------------
__global__ __launch_bounds__(TPB) void kv_fused(
    const float* __restrict__ kin, const float* __restrict__ vin,
    const u16* __restrict__ WkT, const u16* __restrict__ WvT,
    const float* __restrict__ Wk, const float* __restrict__ bk_,
    const float* __restrict__ Wv, const float* __restrict__ bv_,
    u16* __restrict__ klm, u16* __restrict__ vlmT)
{
  __shared__ u16 sA[128*64];     // 16 KB
  __shared__ u16 sB[256*64];     // 32 KB
  __shared__ float sf0[256];     // bias
  __shared__ float sf1[64];      // freqs

  const int tid  = threadIdx.x;
  const int lane = tid & 63;
  const int w    = tid >> 6;
  const int lh   = lane & 15;
  const int lq   = lane >> 4;
  const int bid  = blockIdx.x;

  if (bid < cB*224) {
    // ---------------- kvk branch ----------------
    const int b    = bid / 224;
    const int t    = bid % 224;
    const int row0 = t * 128;
    const int ty0  = (t & 31) * 2;

    if (tid < 64) {
      sf1[tid] = __expf(-(float)tid * cLOGTH);
      *(float4*)&sf0[tid*4] = *(const float4*)(bk_ + tid*4);
    }

    stageW64(WkT, sB, tid);

    {
      const int row = tid >> 1, half = tid & 1;
      const float* src = kin + ((size_t)b*cNK + row0 + row)*cKV + half*32;
      u16 tmp[32];
      #pragma unroll
      for (int u = 0; u < 8; ++u) {
        float4 v = *(const float4*)(src + u*4);
        tmp[u*4+0]=f2bf(v.x); tmp[u*4+1]=f2bf(v.y); tmp[u*4+2]=f2bf(v.z); tmp[u*4+3]=f2bf(v.w);
      }
      #pragma unroll
      for (int s4 = 0; s4 < 4; ++s4) {
        int s = half*4 + s4;
        int p = s ^ (row & 7);
        *(bf16x8*)(sA + row*64 + p*8) = *(bf16x8*)&tmp[s4*8];
      }
    }
    __syncthreads();

    f32x4 acc[2][16];
    #pragma unroll
    for (int rf = 0; rf < 2; ++rf)
      #pragma unroll
      for (int cf = 0; cf < 16; ++cf) acc[rf][cf] = (f32x4){0,0,0,0};

    #pragma unroll
    for (int kk2 = 0; kk2 < 2; ++kk2) {
      bf16x8 af[2];
      #pragma unroll
      for (int rf = 0; rf < 2; ++rf) {
        const int row_a = 64*rf + 16*w + lh;
        int p = (kk2*4 + lq) ^ (row_a & 7);
        af[rf] = *(const bf16x8*)(sA + row_a*64 + p*8);
      }
      #pragma unroll
      for (int cf = 0; cf < 16; ++cf) {
        const int n = 16*cf + lh;
        bf16x8 bf = *(const bf16x8*)(sB + n*64 + ((kk2*4 + lq) ^ (n & 7))*8);
        acc[0][cf] = __builtin_amdgcn_mfma_f32_16x16x32_bf16(af[0], bf, acc[0][cf], 0,0,0);
        acc[1][cf] = __builtin_amdgcn_mfma_f32_16x16x32_bf16(af[1], bf, acc[1][cf], 0,0,0);
      }
    }

    const int tx_base = 16*w + 4*lq;
    const int l_base  = 32*t + 8*w + 2*lq;
    #pragma unroll
    for (int cf = 0; cf < 16; ++cf) {
      const int c  = 16*cf + lh;
      const float fr = sf1[(c >> 1) & 63];
      const float bb = sf0[c];
      float outp[2][4];
      if (cf < 8) {
        float snv[4], csv[4];
        #pragma unroll
        for (int i = 0; i < 4; ++i)
          __sincosf((float)(tx_base + i) * fr, &snv[i], &csv[i]);
        #pragma unroll
        for (int rf = 0; rf < 2; ++rf)
          #pragma unroll
          for (int i = 0; i < 4; ++i) {
            float v = acc[rf][cf][i] + bb;
            float pr = dpp_mov<0xB1>(v);
            outp[rf][i] = (lh & 1) ? (pr*snv[i] + v*csv[i]) : (v*csv[i] - pr*snv[i]);
          }
      } else {
        #pragma unroll
        for (int rf = 0; rf < 2; ++rf) {
          float sn, cs;
          __sincosf((float)(ty0 + rf) * fr, &sn, &cs);
          #pragma unroll
          for (int i = 0; i < 4; ++i) {
            float v = acc[rf][cf][i] + bb;
            float pr = dpp_mov<0xB1>(v);
            outp[rf][i] = (lh & 1) ? (pr*sn + v*cs) : (v*cs - pr*sn);
          }
        }
      }
      float o0 = (outp[0][0] + outp[0][1] + outp[1][0] + outp[1][1]) * 0.25f + cKOFF;
      float o1 = (outp[0][2] + outp[0][3] + outp[1][2] + outp[1][3]) * 0.25f + cKOFF;
      const int sl0 = (c >> 3) ^ (l_base & 7);
      const int sl1 = (c >> 3) ^ ((l_base + 1) & 7);
      klm[((size_t)b*cNLM + l_base    )*256 + sl0*8 + (c & 7)] = f2bf(o0);
      klm[((size_t)b*cNLM + l_base + 1)*256 + sl1*8 + (c & 7)] = f2bf(o1);
    }

  } else if (bid < cB*224 + cB*56) {
    // ---------------- kvv branch ----------------
    const int idx = bid - cB*224;
    const int b   = idx / 56;
    const int l0  = (idx % 56) * 128;

    if (tid < 64) *(float4*)&sf0[tid*4] = *(const float4*)(bv_ + tid*4);

    stageW64(WvT, sB, tid);

    {
      const int row = tid >> 1, half = tid & 1;
      const int lm = l0 + row;
      const int f = lm >> 10, idx2 = lm & 1023;
      const int p_ = idx2 >> 5, q_ = idx2 & 31;
      const size_t r0 = (size_t)b*cNK + f*4096 + (2*p_)*64 + 2*q_;
      const float* s0 = vin + r0*cKV + half*32;
      u16 tmp[32];
      #pragma unroll
      for (int u = 0; u < 8; ++u) {
        float4 a = *(const float4*)(s0 + u*4);
        float4 a1 = *(const float4*)(s0 + 64 + u*4);
        float4 a2 = *(const float4*)(s0 + 64*64 + u*4);
        float4 a3 = *(const float4*)(s0 + 65*64 + u*4);
        tmp[u*4+0] = f2bf((a.x + a1.x + a2.x + a3.x) * 0.25f);
        tmp[u*4+1] = f2bf((a.y + a1.y + a2.y + a3.y) * 0.25f);
        tmp[u*4+2] = f2bf((a.z + a1.z + a2.z + a3.z) * 0.25f);
        tmp[u*4+3] = f2bf((a.w + a1.w + a2.w + a3.w) * 0.25f);
      }
      #pragma unroll
      for (int s4 = 0; s4 < 4; ++s4) {
        int s = half*4 + s4;
        int p = s ^ (row & 7);
        *(bf16x8*)(sA + row*64 + p*8) = *(bf16x8*)&tmp[s4*8];
      }
    }
    __syncthreads();

    f32x4 acc[2][16];
    #pragma unroll
    for (int rf = 0; rf < 2; ++rf)
      #pragma unroll
      for (int cf = 0; cf < 16; ++cf) acc[rf][cf] = (f32x4){0,0,0,0};

    #pragma unroll
    for (int kk2 = 0; kk2 < 2; ++kk2) {
      bf16x8 af[2];
      #pragma unroll
      for (int rf = 0; rf < 2; ++rf) {
        const int row_a = 32*w + 16*rf + lh;
        int p = (kk2*4 + lq) ^ (row_a & 7);
        af[rf] = *(const bf16x8*)(sA + row_a*64 + p*8);
      }
      #pragma unroll
      for (int cf = 0; cf < 16; ++cf) {
        const int n = 16*cf + lh;
        bf16x8 bf = *(const bf16x8*)(sB + n*64 + ((kk2*4 + lq) ^ (n & 7))*8);
        acc[0][cf] = __builtin_amdgcn_mfma_f32_16x16x32_bf16(af[0], bf, acc[0][cf], 0,0,0);
        acc[1][cf] = __builtin_amdgcn_mfma_f32_16x16x32_bf16(af[1], bf, acc[1][cf], 0,0,0);
      }
    }

    #pragma unroll
    for (int rf = 0; rf < 2; ++rf) {
      const int key0 = l0 + 32*w + 16*rf + 4*lq;
      #pragma unroll
      for (int cf = 0; cf < 16; ++cf) {
        const int c = 16*cf + lh;
        const float bb = sf0[c];
        ushort4 o;
        o.x = f2bf(acc[rf][cf][0] + bb);
        o.y = f2bf(acc[rf][cf][1] + bb);
        o.z = f2bf(acc[rf][cf][2] + bb);
        o.w = f2bf(acc[rf][cf][3] + bb);
        *(ushort4*)(vlmT + ((size_t)b*256 + c)*cNLM + key0) = o;
      }
    }

  } else {
    // ---------------- tail branch ----------------
    const int idx = bid - (cB*224 + cB*56);
    const int b   = idx >> 4;
    const int l0  = cNPOOL + (idx & 15) * 4;

    float* skf = (float*)sA;            // [4][68]
    float* svf = (float*)sA + 4*68;     // [4][68]

    if (tid < 64) {
      int r = tid >> 4, c4 = tid & 15;
      const size_t off = ((size_t)b*cNK + cNKR + (l0 - cNPOOL) + r)*cKV + c4*4;
      *(float4*)&skf[r*68 + c4*4] = *(const float4*)(kin + off);
      *(float4*)&svf[r*68 + c4*4] = *(const float4*)(vin + off);
    }
    __syncthreads();

    const int c0 = (tid & 63) * 4;
    const int rg = tid >> 6;
    const float4 bbk = *(const float4*)(bk_ + c0);
    const float4 bbv = *(const float4*)(bv_ + c0);

    float4 ak = {0,0,0,0}, av = {0,0,0,0};
    for (int i = 0; i < 64; i += 4) {
      const float4 k0w = *(const float4*)(Wk + (size_t)(i+0)*256 + c0);
      const float4 k1w = *(const float4*)(Wk + (size_t)(i+1)*256 + c0);
      const float4 k2w = *(const float4*)(Wk + (size_t)(i+2)*256 + c0);
      const float4 k3w = *(const float4*)(Wk + (size_t)(i+3)*256 + c0);
      const float4 v0w = *(const float4*)(Wv + (size_t)(i+0)*256 + c0);
      const float4 v1w = *(const float4*)(Wv + (size_t)(i+1)*256 + c0);
      const float4 v2w = *(const float4*)(Wv + (size_t)(i+2)*256 + c0);
      const float4 v3w = *(const float4*)(Wv + (size_t)(i+3)*256 + c0);
      mac4(ak, *(const float4*)&skf[rg*68 + i], k0w,k1w,k2w,k3w);
      mac4(av, *(const float4*)&svf[rg*68 + i], v0w,v1w,v2w,v3w);
    }
    ak.x += bbk.x; ak.y += bbk.y; ak.z += bbk.z; ak.w += bbk.w;
    av.x += bbv.x; av.y += bbv.y; av.z += bbv.z; av.w += bbv.w;

    const int key = l0 + rg;
    {
      int slot = (c0 >> 3) ^ (key & 7);
      u16* dst = klm + (size_t)(b*cNLM + key)*256 + slot*8 + (c0 & 7);
      ushort4 w4; w4.x = f2bf(ak.x); w4.y = f2bf(ak.y); w4.z = f2bf(ak.z); w4.w = f2bf(ak.w);
      *(ushort4*)dst = w4;
    }
    vlmT[(size_t)(b*256 + c0+0)*cNLM + key] = f2bf(av.x);
    vlmT[(size_t)(b*256 + c0+1)*cNLM + key] = f2bf(av.y);
    vlmT[(size_t)(b*256 + c0+2)*cNLM + key] = f2bf(av.z);
    vlmT[(size_t)(b*256 + c0+3)*cNLM + key] = f2bf(av.w);
  }
}

// ---------------------------------------------------------------------------
// MFMA flash attention (R4/R11 proven config: 4 waves x 32 q-rows, 256 thr,
// KSPLIT=4, defer-max THR=8, l via ones-MFMA, setprio on MFMA clusters,
// stage issued AFTER the QK cluster — verified placement).
// ---------------------------------------------------------------------------
__device__ __forceinline__ void stage_tile(int b, int kt0, int w, int lane,
    u16* sKbuf, u16* sVbuf, const u16* __restrict__ klm, const u16* __restrict__ vlmT)
{
  {
    const u16* g = klm + ((size_t)(b*cNLM + kt0 + 8*w))*256 + lane*8;
    u16* l = sKbuf + 8*w*256;
    #pragma unroll
    for (int i = 0; i < 4; ++i)
      gl_lds16(g + i*512, l + i*512);
  }
  {
    const u16* g = vlmT + ((size_t)(b*256 + 64*w + (lane>>2)))*cNLM + kt0 + (lane&3)*8;
    u16* l = sVbuf + 64*w*32;
    #pragma unroll
    for (int i = 0; i < 4; ++i)
      gl_lds16(g + (size_t)16*i*cNLM, l + i*512);
  }
}

__global__ __launch_bounds__(TPB, 2) void attn_kernel(
    const u16* __restrict__ qr, const u16* __restrict__ klm,
    const u16* __restrict__ vlmT, u16* __restrict__ Opart, float2* __restrict__ ml)
{
  __shared__ u16 sK[2][32*256];
  __shared__ u16 sV[2][256*32];
  __shared__ unsigned sP[4][32*16];

  const int tid  = threadIdx.x;
  const int lane = tid & 63;
  const int w    = tid >> 6;
  const int lh   = lane & 15;
  const int lq   = lane >> 4;

  const int bx    = blockIdx.x;
  const int split = bx & 3;
  const int qb    = (bx >> 2) & 31;
  const int b     = bx >> 7;

  const int ts0 = split*56 + (split < 2 ? split : 2);
  const int len = 56 + (split < 2 ? 1 : 0);
  const int qw  = qb*cQT + 32*w;

  bf16x8 qf[2][8];
  {
    const u16* qbase = qr + (size_t)(b*cNQ + qw + lh)*256 + lq*8;
    #pragma unroll
    for (int rf = 0; rf < 2; ++rf)
      #pragma unroll
      for (int kk = 0; kk < 8; ++kk)
        qf[rf][kk] = *(const bf16x8*)(qbase + (size_t)rf*16*256 + kk*32);
  }

  bf16x8 onesf;
  #pragma unroll
  for (int j = 0; j < 8; ++j) onesf[j] = (short)0x3F80;

  f32x4 O[2][16];
  #pragma unroll
  for (int rf = 0; rf < 2; ++rf)
    #pragma unroll
    for (int cf = 0; cf < 16; ++cf)
      O[rf][cf] = (f32x4){0.f,0.f,0.f,0.f};

  f32x4 lacc[2];
  lacc[0] = (f32x4){0,0,0,0}; lacc[1] = (f32x4){0,0,0,0};
  float m_[2][4];
  #pragma unroll
  for (int rf = 0; rf < 2; ++rf)
    #pragma unroll
    for (int i = 0; i < 4; ++i) m_[rf][i] = -INFINITY;

  stage_tile(b, ts0*cKT, w, lane, sK[0], sV[0], klm, vlmT);
  __syncthreads();

  int cur = 0;
  for (int t = 0; t < len; ++t) {
    f32x4 S[2][2];
    S[0][0] = (f32x4){0,0,0,0}; S[0][1] = (f32x4){0,0,0,0};
    S[1][0] = (f32x4){0,0,0,0}; S[1][1] = (f32x4){0,0,0,0};
    __builtin_amdgcn_s_setprio(1);
    #pragma unroll
    for (int kk = 0; kk < 8; ++kk) {
      #pragma unroll
      for (int cf = 0; cf < 2; ++cf) {
        const int r = 16*cf + lh;
        const int slot = (4*kk + lq) ^ (r & 7);
        bf16x8 kf = *(const bf16x8*)(sK[cur] + r*256 + slot*8);
        S[0][cf] = __builtin_amdgcn_mfma_f32_16x16x32_bf16(qf[0][kk], kf, S[0][cf], 0,0,0);
        S[1][cf] = __builtin_amdgcn_mfma_f32_16x16x32_bf16(qf[1][kk], kf, S[1][cf], 0,0,0);
      }
    }
    __builtin_amdgcn_s_setprio(0);

    if (t+1 < len) stage_tile(b, (ts0+t+1)*cKT, w, lane, sK[cur^1], sV[cur^1], klm, vlmT);

    bool need = false;
    #pragma unroll
    for (int rf = 0; rf < 2; ++rf)
      #pragma unroll
      for (int cf = 0; cf < 2; ++cf)
        #pragma unroll
        for (int i = 0; i < 4; ++i)
          need |= (S[rf][cf][i] > m_[rf][i] + cTHR);

    if (__ballot(need)) {   // rare: recompute max, rescale O and l
      #pragma unroll
      for (int rf = 0; rf < 2; ++rf) {
        float al[4];
        #pragma unroll
        for (int i = 0; i < 4; ++i) {
          float tm = redmax16(fmaxf(S[rf][0][i], S[rf][1][i]));
          float mn = fmaxf(m_[rf][i], tm);
          al[i] = __expf(m_[rf][i] - mn);
          m_[rf][i] = mn;
          lacc[rf][i] *= al[i];
        }
        #pragma unroll
        for (int cf = 0; cf < 16; ++cf) {
          O[rf][cf][0] *= al[0]; O[rf][cf][1] *= al[1];
          O[rf][cf][2] *= al[2]; O[rf][cf][3] *= al[3];
        }
      }
    }

    // p = exp(S - m), pack to bf16 -> wave-private sP
    #pragma unroll
    for (int rf = 0; rf < 2; ++rf) {
      f32x4 p0, p1;
      #pragma unroll
      for (int i = 0; i < 4; ++i) {
        p0[i] = __expf(S[rf][0][i] - m_[rf][i]);
        p1[i] = __expf(S[rf][1][i] - m_[rf][i]);
      }
      #pragma unroll
      for (int cf = 0; cf < 2; ++cf) {
        #pragma unroll
        for (int i = 0; i < 4; ++i) {
          float pv = cf ? p1[i] : p0[i];
          float other = dpp_mov<0xB1>(pv);
          if (!(lane & 1)) {
            unsigned u = (unsigned)f2bf(pv) | ((unsigned)f2bf(other) << 16);
            sP[w][(16*rf + 4*lq + i)*16 + (lh >> 1) + 8*cf] = u;
          }
        }
      }
    }

    const u16* sPw = (const u16*)sP[w];
    bf16x8 pa0 = *(const bf16x8*)(sPw + lh*32 + lq*8);
    bf16x8 pa1 = *(const bf16x8*)(sPw + (16 + lh)*32 + lq*8);
    __builtin_amdgcn_s_setprio(1);
    lacc[0] = __builtin_amdgcn_mfma_f32_16x16x32_bf16(pa0, onesf, lacc[0], 0,0,0);
    lacc[1] = __builtin_amdgcn_mfma_f32_16x16x32_bf16(pa1, onesf, lacc[1], 0,0,0);
    #pragma unroll
    for (int cf = 0; cf < 16; ++cf) {
      bf16x8 vf = *(const bf16x8*)(sV[cur] + (16*cf + lh)*32 + lq*8);
      O[0][cf] = __builtin_amdgcn_mfma_f32_16x16x32_bf16(pa0, vf, O[0][cf], 0,0,0);
      O[1][cf] = __builtin_amdgcn_mfma_f32_16x16x32_bf16(pa1, vf, O[1][cf], 0,0,0);
    }
    __builtin_amdgcn_s_setprio(0);

    __syncthreads();
    cur ^= 1;
  }

  const size_t obase = (size_t)split*(cB*cNQ) + (size_t)b*cNQ;
  #pragma unroll
  for (int rf = 0; rf < 2; ++rf)
    #pragma unroll
    for (int cf = 0; cf < 16; ++cf) {
      #pragma unroll
      for (int i = 0; i < 4; ++i) {
        int row = qw + 16*rf + 4*lq + i;
        Opart[(obase + row)*256 + 16*cf + lh] = f2bf(O[rf][cf][i]);
      }
    }
  if (lh == 0) {
    #pragma unroll
    for (int rf = 0; rf < 2; ++rf)
      #pragma unroll
      for (int i = 0; i < 4; ++i) {
        int row = qw + 16*rf + 4*lq + i;
        ml[obase + row] = make_float2(m_[rf][i], lacc[rf][i]);
      }
  }
}

// ---------------------------------------------------------------------------
// projo_mfma (FUSED combine): out = combine(Opart, ml) @ Wo + bo.
// ---------------------------------------------------------------------------
__global__ __launch_bounds__(128) void projo_mfma(
    const u16* __restrict__ Opart, const float2* __restrict__ ml,
    const u16* __restrict__ WThi, const u16* __restrict__ WTlo,
    const float* __restrict__ bias, float* __restrict__ Y)
{
  __shared__ u16 lds[49152];
  u16* sAhi = lds;
  u16* sAlo = lds + 16384;
  u16* sB   = lds + 32768;
  __shared__ float sbo[256];
  __shared__ float sWt[64][4];
  __shared__ float sInv[64];

  const int tid  = threadIdx.x;
  const int lane = tid & 63;
  const int w    = tid >> 6;
  const int lh   = lane & 15;
  const int lq   = lane >> 4;
  const int row0 = blockIdx.x * 64;

  if (tid < 64) *(float4*)&sbo[tid*4] = *(const float4*)(bias + tid*4);

  if (tid < 64) {
    const int R = row0 + tid;
    float2 mlv[cKSPLIT];
    float M = -INFINITY;
    #pragma unroll
    for (int s = 0; s < cKSPLIT; ++s) {
      mlv[s] = ml[(size_t)s*(cB*cNQ) + R];
      M = fmaxf(M, mlv[s].x);
    }
    float L = 0.f;
    #pragma unroll
    for (int s = 0; s < cKSPLIT; ++s) {
      float wg = __expf(mlv[s].x - M);
      sWt[tid][s] = wg;
      L += wg * mlv[s].y;
    }
    sInv[tid] = 1.f / L;
  }
  __syncthreads();

  {
    const int rl = tid >> 6;
    const int c0 = (tid & 63) * 4;
    const int s4 = c0 >> 3;
    #pragma unroll 4
    for (int rr = 0; rr < 64; rr += 2) {
      const int r = rr + rl;
      const int R = row0 + r;
      const float w0 = sWt[r][0], w1 = sWt[r][1], w2 = sWt[r][2], w3 = sWt[r][3];
      const float iv = sInv[r];
      const ushort4 q0 = *(const ushort4*)(Opart + ((size_t)0*(cB*cNQ) + R)*256 + c0);
      const ushort4 q1 = *(const ushort4*)(Opart + ((size_t)1*(cB*cNQ) + R)*256 + c0);
      const ushort4 q2 = *(const ushort4*)(Opart + ((size_t)2*(cB*cNQ) + R)*256 + c0);
      const ushort4 q3 = *(const ushort4*)(Opart + ((size_t)3*(cB*cNQ) + R)*256 + c0);
      float xv[4];
      xv[0] = (w0*bf2f(q0.x) + w1*bf2f(q1.x) + w2*bf2f(q2.x) + w3*bf2f(q3.x)) * iv;
      xv[1] = (w0*bf2f(q0.y) + w1*bf2f(q1.y) + w2*bf2f(q2.y) + w3*bf2f(q3.y)) * iv;
      xv[2] = (w0*bf2f(q0.z) + w1*bf2f(q1.z) + w2*bf2f(q2.z) + w3*bf2f(q3.z)) * iv;
      xv[3] = (w0*bf2f(q0.w) + w1*bf2f(q1.w) + w2*bf2f(q2.w) + w3*bf2f(q3.w)) * iv;
      ushort4 h, l;
      #pragma unroll
      for (int j = 0; j < 4; ++j) {
        u16 hb = f2bf(xv[j]);
        u16 lb = f2bf(xv[j] - bf2f(hb));
        ((u16*)&h)[j] = hb; ((u16*)&l)[j] = lb;
      }
      const int p = (s4 & ~7) | ((s4 & 7) ^ (r & 7));
      const int off = r*256 + p*8 + (c0 & 4);
      *(ushort4*)(sAhi + off) = h;
      *(ushort4*)(sAlo + off) = l;
    }
  }

  f32x4 acc[2][16];
  #pragma unroll
  for (int rf = 0; rf < 2; ++rf)
    #pragma unroll
    for (int cf = 0; cf < 16; ++cf) acc[rf][cf] = (f32x4){0,0,0,0};

  __syncthreads();

  for (int st = 0; st < 4; ++st) {
    __syncthreads();
    stageB(WThi, st, sB, tid);
    __syncthreads();
    #pragma unroll
    for (int kk2 = 0; kk2 < 2; ++kk2) {
      bf16x8 ah[2], al[2];
      #pragma unroll
      for (int rf = 0; rf < 2; ++rf) {
        const int row_a = 32*w + 16*rf + lh;
        int p = st*8 + ((kk2*4 + lq) ^ (row_a & 7));
        ah[rf] = *(const bf16x8*)(sAhi + row_a*256 + p*8);
        al[rf] = *(const bf16x8*)(sAlo + row_a*256 + p*8);
      }
      #pragma unroll
      for (int cf = 0; cf < 16; ++cf) {
        const int n = 16*cf + lh;
        bf16x8 bf = *(const bf16x8*)(sB + n*64 + (((kk2*4 + lq) ^ (n & 7)))*8);
        #pragma unroll
        for (int rf = 0; rf < 2; ++rf) {
          acc[rf][cf] = __builtin_amdgcn_mfma_f32_16x16x32_bf16(ah[rf], bf, acc[rf][cf], 0,0,0);
          acc[rf][cf] = __builtin_amdgcn_mfma_f32_16x16x32_bf16(al[rf], bf, acc[rf][cf], 0,0,0);
        }
      }
    }
  }
  for (int st = 0; st < 4; ++st) {
    __syncthreads();
    stageB(WTlo, st, sB, tid);
    __syncthreads();
    #pragma unroll
    for (int kk2 = 0; kk2 < 2; ++kk2) {
      bf16x8 ah[2];
      #pragma unroll
      for (int rf = 0; rf < 2; ++rf) {
        const int row_a = 32*w + 16*rf + lh;
        int p = st*8 + ((kk2*4 + lq) ^ (row_a & 7));
        ah[rf] = *(const bf16x8*)(sAhi + row_a*256 + p*8);
      }
      #pragma unroll
      for (int cf = 0; cf < 16; ++cf) {
        const int n = 16*cf + lh;
        bf16x8 bf = *(const bf16x8*)(sB + n*64 + (((kk2*4 + lq) ^ (n & 7)))*8);
        #pragma unroll
        for (int rf = 0; rf < 2; ++rf)
          acc[rf][cf] = __builtin_amdgcn_mfma_f32_16x16x32_bf16(ah[rf], bf, acc[rf][cf], 0,0,0);
      }
    }
  }

  #pragma unroll
  for (int rf = 0; rf < 2; ++rf)
    #pragma unroll
    for (int cf = 0; cf < 16; ++cf) {
      const int col = 16*cf + lh;
      #pragma unroll
      for (int i = 0; i < 4; ++i) {
        int row = row0 + 32*w + 16*rf + 4*lq + i;
        Y[(size_t)row*256 + col] = acc[rf][cf][i] + sbo[col];
      }
    }
}

// ---------------------------------------------------------------------------
extern "C" void kernel_launch(void* const* d_in, const int* in_sizes, int n_in,
                              void* d_out, int out_size, void* d_ws, size_t ws_size,
                              hipStream_t stream)
{
  const float* q  = (const float*)d_in[0];
  const float* k  = (const float*)d_in[1];
  const float* v  = (const float*)d_in[2];
  const float* Wq = (const float*)d_in[3];
  const float* bq = (const float*)d_in[4];
  const float* Wk = (const float*)d_in[5];
  const float* bk = (const float*)d_in[6];
  const float* Wv = (const float*)d_in[7];
  const float* bv = (const float*)d_in[8];
  const float* Wo = (const float*)d_in[9];
  const float* bo = (const float*)d_in[10];
  float* out = (float*)d_out;

  constexpr size_t qrB    = (size_t)cB*cNQ*256*sizeof(u16);        //  8.39 MB
  constexpr size_t klmB   = (size_t)cB*cNLM*256*sizeof(u16);       // 14.81 MB
  constexpr size_t vlmB   = klmB;
  constexpr size_t opartB = (size_t)cKSPLIT*cB*cNQ*256*sizeof(u16);// 33.55 MB
  constexpr size_t mlB    = (size_t)cKSPLIT*cB*cNQ*sizeof(float2); //  0.52 MB

  char* w8 = (char*)d_ws;
  u16*    qr    = (u16*)(w8);
  u16*    klm   = (u16*)(w8 + qrB);
  u16*    vlmT  = (u16*)(w8 + qrB + klmB);
  u16*    Opart = (u16*)(w8 + qrB + klmB + vlmB);
  float2* mlp   = (float2*)(w8 + qrB + klmB + vlmB + opartB);
  u16*    WqT   = (u16*)(w8 + qrB + klmB + vlmB + opartB + mlB);
  u16*    WoThi = WqT   + 256*256;
  u16*    WoTlo = WoThi + 256*256;
  u16*    WkT   = WoTlo + 256*256;
  u16*    WvT   = WkT   + 256*64;

  wprep_kernel<<<160, TPB, 0, stream>>>(Wq, Wo, Wk, Wv, WqT, WoThi, WoTlo, WkT, WvT);
  projq_mfma  <<<cNQ/16, 128, 0, stream>>>(q, WqT, bq, qr);
  kv_fused    <<<cB*224 + cB*56 + cB*16, TPB, 0, stream>>>(
                  k, v, WkT, WvT, Wk, bk, Wv, bv, klm, vlmT);
  attn_kernel <<<cB*(cNQ/cQT)*cKSPLIT, TPB, 0, stream>>>(qr, klm, vlmT, Opart, mlp);
  projo_mfma  <<<(cB*cNQ)/64, 128, 0, stream>>>(Opart, mlp, WoThi, WoTlo, bo, out);
}